// Round 8
// baseline (132.867 us; speedup 1.0000x reference)
//
#include <hip/hip_runtime.h>
#include <hip/hip_bf16.h>

// out[bh][m][d] = sum_k x1[bh][m][k] * x2[bh][k][d];  BH=32, S=2048(M,K), D=64(N), fp32.
// HBM-bound on x1 (537 MB, zero reuse). bf16 MFMA 16x16x32, fp32 acc.
//
// R8 = R2's proven skeleton (BM=128, BK=128, 512 thr, double-buffered LDS,
// per-step __syncthreads, register ping-pong A prefetch) with the x2 staging
// path replaced by DMA:
//   pre-kernel: x2 [bh][k][d] fp32 -> x2t [bh][d][k] bf16 in d_ws (R4-proven).
//   GEMM: stage x2t -> LDS via __builtin_amdgcn_global_load_lds (16B), 2 calls
//   per wave per K-step. No staging VGPRs, no f2bf, no ds_write on that path.
//   LDS tile is granule-XOR swizzled (c ^= d&7) via PRE-SWIZZLED SOURCE
//   addresses (DMA dest must be linear; rule: both-sides-or-neither), read
//   with matching XOR -> 2 lanes/bank on ds_read_b128 (free).

#define S_DIM 2048
#define D_DIM 64
#define BM    128
#define BK    128
#define NT    (S_DIM / BK)   // 16 K-steps
#define LDB   (BK + 8)       // fallback kernel only

typedef __attribute__((ext_vector_type(8))) short short8;
typedef __attribute__((ext_vector_type(4))) short short4v;
typedef __attribute__((ext_vector_type(4))) float f32x4;

__device__ __forceinline__ short f2bf(float x) {
    return __builtin_bit_cast(short, __float2bfloat16(x));
}

__device__ __forceinline__ void dma16(const void* g, void* l) {
    __builtin_amdgcn_global_load_lds(
        (const __attribute__((address_space(1))) void*)g,
        (__attribute__((address_space(3))) void*)l, 16, 0, 0);
}

// ---------------- kernel 1: transpose + bf16 convert of x2 (R4-proven) -----
__global__ __launch_bounds__(256)
void x2_transpose_kernel(const float* __restrict__ x2, short* __restrict__ x2t) {
    __shared__ float tile[64][65];
    int bh = blockIdx.x >> 5;            // 32 k-blocks per bh
    int kb = (blockIdx.x & 31) * 64;
    int t  = threadIdx.x;
    int d  = t & 63;
    int k4 = t >> 6;                     // 0..3
    const float* src = x2 + ((size_t)bh * S_DIM + kb) * D_DIM + d;
#pragma unroll
    for (int i = 0; i < 16; ++i)
        tile[i * 4 + k4][d] = src[(size_t)(i * 4 + k4) * D_DIM];
    __syncthreads();
    int dcol = t >> 2;                   // 0..63
    int kg   = (t & 3) * 16;             // 0,16,32,48
    short8 v0, v1;
#pragma unroll
    for (int j = 0; j < 8; ++j) {
        v0[j] = f2bf(tile[kg + j][dcol]);
        v1[j] = f2bf(tile[kg + 8 + j][dcol]);
    }
    short* dst = x2t + ((size_t)bh * D_DIM + dcol) * S_DIM + kb + kg;
    *(short8*)dst = v0;
    *(short8*)(dst + 8) = v1;
}

// ---------------- kernel 2: GEMM with DMA-staged, swizzled LDS B ----------
__global__ __launch_bounds__(512, 4)
void pv_gemm_dma_kernel(const float* __restrict__ x1,
                        const short* __restrict__ x2t,
                        float* __restrict__ out) {
    // 2 buffers x 1024 granules x 16B = 32 KB. Granule g holds logical
    // (d = g>>4, c = (g&15) ^ (d&7)), c = k/8. Linear DMA dest; swizzle is
    // baked into the per-lane SOURCE address and re-applied on read.
    __shared__ short ldsB[2][8192];

    // XCD-aware bijective swizzle (512 % 8 == 0): 4 bh per XCD.
    int bid = blockIdx.x;
    int lb  = (bid & 7) * 64 + (bid >> 3);
    int bh   = lb >> 4;
    int mblk = lb & 15;
    int m0   = mblk * BM;

    int tid  = threadIdx.x;
    int lane = tid & 63;
    int w    = tid >> 6;         // wave 0..7

    int ll = lane & 15;
    int lh = lane >> 4;          // 0..3
    int xr = ll & 7;             // = d&7 for every d = ni*16+ll

    // ---- DMA source addresses (per lane, per call j=0,1)
    // granule g = (2w+j)*64 + lane; src = x2t_bh + (g>>4)*4096B + c_log*16B
    const char* sbase = (const char*)(x2t + (size_t)bh * D_DIM * S_DIM);
    int g0 = (2 * w + 0) * 64 + lane;
    int g1 = (2 * w + 1) * 64 + lane;
    const char* s0 = sbase + (size_t)(g0 >> 4) * 4096
                   + (((g0 & 15) ^ ((g0 >> 4) & 7)) << 4);
    const char* s1 = sbase + (size_t)(g1 >> 4) * 4096
                   + (((g1 & 15) ^ ((g1 >> 4) & 7)) << 4);

    // ---- A fragment (mfma 16x16x32 bf16): row = ll, k = kk*32 + lh*8 + j
    const float* abase = x1 + ((size_t)bh * S_DIM + m0 + w * 16 + ll) * S_DIM + lh * 8;

    f32x4 acc[4];
#pragma unroll
    for (int i = 0; i < 4; ++i) acc[i] = (f32x4){0.f, 0.f, 0.f, 0.f};

    // ---- prologue: DMA-stage tile 0 into buf 0; load A tile 0
    dma16(s0, &ldsB[0][(2 * w + 0) * 512]);
    dma16(s1, &ldsB[0][(2 * w + 1) * 512]);

    f32x4 rA0[8], rA1[8];
#pragma unroll
    for (int kk = 0; kk < 4; ++kk) {
        rA0[2 * kk]     = *(const f32x4*)(abase + kk * 32);
        rA0[2 * kk + 1] = *(const f32x4*)(abase + kk * 32 + 4);
    }

// One K-step. __syncthreads (vmcnt+lgkm drain) guarantees tile T staged in
// RBUF and all reads of RBUF^1 done; then DMA tile T+1 into RBUF^1 and
// prefetch A(T+1) while computing on RBUF.
#define ITER(T, RBUF, RA_CUR, RA_NXT)                                        \
    {                                                                        \
        __syncthreads();                                                     \
        if ((T) + 1 < NT) {                                                  \
            dma16(s0 + ((T) + 1) * 256, &ldsB[(RBUF) ^ 1][(2 * w + 0) * 512]);\
            dma16(s1 + ((T) + 1) * 256, &ldsB[(RBUF) ^ 1][(2 * w + 1) * 512]);\
            const float* an = abase + (size_t)((T) + 1) * BK;                \
            _Pragma("unroll")                                                \
            for (int kk = 0; kk < 4; ++kk) {                                 \
                RA_NXT[2 * kk]     = *(const f32x4*)(an + kk * 32);          \
                RA_NXT[2 * kk + 1] = *(const f32x4*)(an + kk * 32 + 4);      \
            }                                                                \
        }                                                                    \
        _Pragma("unroll")                                                    \
        for (int kk = 0; kk < 4; ++kk) {                                     \
            int cph = (kk * 4 + lh) ^ xr;                                    \
            const short* bq = &ldsB[RBUF][(ll * 16 + cph) * 8];              \
            short8 vb0 = *(const short8*)(bq);                               \
            short8 vb1 = *(const short8*)(bq + 2048);                        \
            short8 vb2 = *(const short8*)(bq + 4096);                        \
            short8 vb3 = *(const short8*)(bq + 6144);                        \
            short8 a;                                                        \
            a[0] = f2bf(RA_CUR[2 * kk][0]);                                  \
            a[1] = f2bf(RA_CUR[2 * kk][1]);                                  \
            a[2] = f2bf(RA_CUR[2 * kk][2]);                                  \
            a[3] = f2bf(RA_CUR[2 * kk][3]);                                  \
            a[4] = f2bf(RA_CUR[2 * kk + 1][0]);                              \
            a[5] = f2bf(RA_CUR[2 * kk + 1][1]);                              \
            a[6] = f2bf(RA_CUR[2 * kk + 1][2]);                              \
            a[7] = f2bf(RA_CUR[2 * kk + 1][3]);                              \
            acc[0] = __builtin_amdgcn_mfma_f32_16x16x32_bf16(a, vb0, acc[0], 0, 0, 0); \
            acc[1] = __builtin_amdgcn_mfma_f32_16x16x32_bf16(a, vb1, acc[1], 0, 0, 0); \
            acc[2] = __builtin_amdgcn_mfma_f32_16x16x32_bf16(a, vb2, acc[2], 0, 0, 0); \
            acc[3] = __builtin_amdgcn_mfma_f32_16x16x32_bf16(a, vb3, acc[3], 0, 0, 0); \
        }                                                                    \
    }

    for (int t = 0; t < NT; t += 2) {
        ITER(t,     0, rA0, rA1);
        ITER(t + 1, 1, rA1, rA0);
    }
#undef ITER

    // ---- epilogue: C/D layout col = ll, row = lh*4 + r
    int r0 = m0 + w * 16 + lh * 4;
    float* ob = out + ((size_t)bh * S_DIM + r0) * D_DIM + ll;
#pragma unroll
    for (int ni = 0; ni < 4; ++ni) {
#pragma unroll
        for (int r = 0; r < 4; ++r)
            ob[(size_t)r * D_DIM + ni * 16] = acc[ni][r];
    }
}

// ---------------- fallback (R2 kernel, proven 116.8 us): ws too small ------
__global__ __launch_bounds__(512, 4)
void pv_gemm_lds_kernel(const float* __restrict__ x1,
                        const float* __restrict__ x2,
                        float* __restrict__ out) {
    __shared__ short lds_b[2][D_DIM][LDB];
    int bid = blockIdx.x;
    int lb  = (bid & 7) * 64 + (bid >> 3);
    int bh   = lb >> 4;
    int mblk = lb & 15;
    int m0   = mblk * BM;
    int tid  = threadIdx.x;
    int lane = tid & 63;
    int w    = tid >> 6;
    int sd  = tid & 63;
    int skb = tid >> 6;
    const float* x2base = x2 + (size_t)bh * S_DIM * D_DIM + sd;
    int arow = m0 + w * 16 + (lane & 15);
    int kgrp = (lane >> 4) * 8;
    const float* abase = x1 + ((size_t)bh * S_DIM + arow) * S_DIM + kgrp;
    f32x4 acc[4];
#pragma unroll
    for (int i = 0; i < 4; ++i) acc[i] = (f32x4){0.f, 0.f, 0.f, 0.f};
    {
        float rs[16];
#pragma unroll
        for (int i = 0; i < 16; ++i)
            rs[i] = x2base[(size_t)(skb * 16 + i) * D_DIM];
#pragma unroll
        for (int j = 0; j < 4; ++j) {
            short4v v;
            v[0] = f2bf(rs[4 * j + 0]); v[1] = f2bf(rs[4 * j + 1]);
            v[2] = f2bf(rs[4 * j + 2]); v[3] = f2bf(rs[4 * j + 3]);
            *(short4v*)&lds_b[0][sd][skb * 16 + 4 * j] = v;
        }
    }
    f32x4 rA0[8], rA1[8];
#pragma unroll
    for (int kk = 0; kk < 4; ++kk) {
        rA0[2 * kk]     = *(const f32x4*)(abase + kk * 32);
        rA0[2 * kk + 1] = *(const f32x4*)(abase + kk * 32 + 4);
    }
#define ITER(T, RBUF, RA_CUR, RA_NXT)                                        \
    {                                                                        \
        __syncthreads();                                                     \
        float rn[16];                                                        \
        if ((T) + 1 < NT) {                                                  \
            const float* p = x2base + (size_t)((T) + 1) * BK * D_DIM;        \
            _Pragma("unroll")                                                \
            for (int i = 0; i < 16; ++i)                                     \
                rn[i] = p[(size_t)(skb * 16 + i) * D_DIM];                   \
            const float* an = abase + (size_t)((T) + 1) * BK;                \
            _Pragma("unroll")                                                \
            for (int kk = 0; kk < 4; ++kk) {                                 \
                RA_NXT[2 * kk]     = *(const f32x4*)(an + kk * 32);          \
                RA_NXT[2 * kk + 1] = *(const f32x4*)(an + kk * 32 + 4);      \
            }                                                                \
        }                                                                    \
        _Pragma("unroll")                                                    \
        for (int kk = 0; kk < 4; ++kk) {                                     \
            short8 a;                                                        \
            a[0] = f2bf(RA_CUR[2 * kk][0]);                                  \
            a[1] = f2bf(RA_CUR[2 * kk][1]);                                  \
            a[2] = f2bf(RA_CUR[2 * kk][2]);                                  \
            a[3] = f2bf(RA_CUR[2 * kk][3]);                                  \
            a[4] = f2bf(RA_CUR[2 * kk + 1][0]);                              \
            a[5] = f2bf(RA_CUR[2 * kk + 1][1]);                              \
            a[6] = f2bf(RA_CUR[2 * kk + 1][2]);                              \
            a[7] = f2bf(RA_CUR[2 * kk + 1][3]);                              \
            _Pragma("unroll")                                                \
            for (int ni = 0; ni < 4; ++ni) {                                 \
                const short8* bp = (const short8*)                           \
                    &lds_b[RBUF][ni * 16 + (lane & 15)][kk * 32 + kgrp];     \
                acc[ni] = __builtin_amdgcn_mfma_f32_16x16x32_bf16(           \
                    a, *bp, acc[ni], 0, 0, 0);                               \
            }                                                                \
        }                                                                    \
        if ((T) + 1 < NT) {                                                  \
            _Pragma("unroll")                                                \
            for (int j = 0; j < 4; ++j) {                                    \
                short4v v;                                                   \
                v[0] = f2bf(rn[4 * j + 0]); v[1] = f2bf(rn[4 * j + 1]);      \
                v[2] = f2bf(rn[4 * j + 2]); v[3] = f2bf(rn[4 * j + 3]);      \
                *(short4v*)&lds_b[(RBUF) ^ 1][sd][skb * 16 + 4 * j] = v;     \
            }                                                                \
        }                                                                    \
    }
    for (int t = 0; t < NT; t += 2) {
        ITER(t,     0, rA0, rA1);
        ITER(t + 1, 1, rA1, rA0);
    }
#undef ITER
    int col0 = lane & 15;
    int r0   = m0 + w * 16 + ((lane >> 4) << 2);
    float* ob = out + ((size_t)bh * S_DIM + r0) * D_DIM + col0;
#pragma unroll
    for (int ni = 0; ni < 4; ++ni) {
#pragma unroll
        for (int r = 0; r < 4; ++r)
            ob[(size_t)r * D_DIM + ni * 16] = acc[ni][r];
    }
}

extern "C" void kernel_launch(void* const* d_in, const int* in_sizes, int n_in,
                              void* d_out, int out_size, void* d_ws, size_t ws_size,
                              hipStream_t stream) {
    const float* x1 = (const float*)d_in[0];   // [2,16,2048,2048] softmax probs
    const float* x2 = (const float*)d_in[1];   // [2,16,2048,64]
    float* out = (float*)d_out;                // [2,16,2048,64]

    const size_t need = (size_t)32 * D_DIM * S_DIM * sizeof(short);  // 8 MB
    if (ws_size >= need) {
        short* x2t = (short*)d_ws;
        hipLaunchKernelGGL(x2_transpose_kernel, dim3(1024), dim3(256), 0, stream,
                           x2, x2t);
        hipLaunchKernelGGL(pv_gemm_dma_kernel, dim3(512), dim3(512), 0, stream,
                           x1, x2t, out);
    } else {
        hipLaunchKernelGGL(pv_gemm_lds_kernel, dim3(512), dim3(512), 0, stream,
                           x1, x2, out);
    }
}

// Round 9
// 122.633 us; speedup vs baseline: 1.0835x; 1.0835x over previous
//
#include <hip/hip_runtime.h>
#include <hip/hip_bf16.h>

// out[bh][m][d] = sum_k x1[bh][m][k] * x2[bh][k][d];  BH=32, S=2048(M,K), D=64(N), fp32.
// HBM-bound on x1 (537 MB, zero reuse). bf16 MFMA 16x16x32, fp32 acc.
//
// R9 = R2 (best so far, 116.8 us) + ONE change: nontemporal policy on the
// zero-reuse streams (x1 loads, out stores). Mechanism: x1 streams ~4 MB per
// K-step through each XCD's 4 MB L2, evicting the x2 slice that 16 same-bh
// blocks re-read (256 MB of intended L2 hits partially spilling to HBM).
// nt = evict-first for x1 lines -> x2 stays L2-resident. x2 staging loads
// remain cached (they ARE the reuse stream). Everything else byte-identical
// to R2: BM=128, BK=128, 512 thr, double-buffered LDS, per-step __syncthreads,
// register ping-pong A prefetch, x2-loads-before-A-loads, XCD swizzle.

#define S_DIM 2048
#define D_DIM 64
#define BM 128
#define BK 128
#define NT (S_DIM / BK)   // 16 K-steps
#define LDB (BK + 8)      // byte stride 272: 16B-aligned, 2-way bank pattern (free)

typedef __attribute__((ext_vector_type(8))) short short8;
typedef __attribute__((ext_vector_type(4))) short short4v;
typedef __attribute__((ext_vector_type(4))) float f32x4;

__device__ __forceinline__ short f2bf(float x) {
    return __builtin_bit_cast(short, __float2bfloat16(x));
}

__global__ __launch_bounds__(512, 4)
void pv_gemm_kernel(const float* __restrict__ x1,
                    const float* __restrict__ x2,
                    float* __restrict__ out) {
    __shared__ short lds_b[2][D_DIM][LDB];   // 34,816 bytes -> 2 blocks/CU

    // XCD-aware bijective swizzle (512 % 8 == 0)
    int bid = blockIdx.x;
    int lb  = (bid & 7) * 64 + (bid >> 3);
    int bh   = lb >> 4;
    int mblk = lb & 15;
    int m0   = mblk * BM;

    int tid  = threadIdx.x;
    int lane = tid & 63;
    int w    = tid >> 6;

    // x2 staging coords: thread t loads column d = t&63, k-block t>>6
    int sd  = tid & 63;
    int skb = tid >> 6;
    const float* x2base = x2 + (size_t)bh * S_DIM * D_DIM + sd;

    // A fragment coords (mfma 16x16x32 bf16: row = lane&15, k = (lane>>4)*8 + j)
    int arow = m0 + w * 16 + (lane & 15);
    int kgrp = (lane >> 4) * 8;
    const float* abase = x1 + ((size_t)bh * S_DIM + arow) * S_DIM + kgrp;

    f32x4 acc[4];
#pragma unroll
    for (int i = 0; i < 4; ++i) acc[i] = (f32x4){0.f, 0.f, 0.f, 0.f};

    // ---- prologue: stage x2 tile 0 into LDS buffer 0 (cached loads)
    {
        float rs[16];
#pragma unroll
        for (int i = 0; i < 16; ++i)
            rs[i] = x2base[(size_t)(skb * 16 + i) * D_DIM];
#pragma unroll
        for (int j = 0; j < 4; ++j) {
            short4v v;
            v[0] = f2bf(rs[4 * j + 0]);
            v[1] = f2bf(rs[4 * j + 1]);
            v[2] = f2bf(rs[4 * j + 2]);
            v[3] = f2bf(rs[4 * j + 3]);
            *(short4v*)&lds_b[0][sd][skb * 16 + 4 * j] = v;
        }
    }

    // ---- prologue: load A tile 0 into rA0 (nontemporal: zero reuse)
    f32x4 rA0[8], rA1[8];
#pragma unroll
    for (int kk = 0; kk < 4; ++kk) {
        rA0[2 * kk]     = __builtin_nontemporal_load((const f32x4*)(abase + kk * 32));
        rA0[2 * kk + 1] = __builtin_nontemporal_load((const f32x4*)(abase + kk * 32 + 4));
    }

// One K-step. RBUF: static LDS read-buffer index. RA_CUR: A regs for this
// step (already loaded). RA_NXT: filled for next step. x2 loads issue FIRST
// (older in vmcnt FIFO), so the ds_write's wait on them leaves A in flight.
#define ITER(T, RBUF, RA_CUR, RA_NXT)                                        \
    {                                                                        \
        __syncthreads();                                                     \
        float rn[16];                                                        \
        if ((T) + 1 < NT) {                                                  \
            const float* p = x2base + (size_t)((T) + 1) * BK * D_DIM;        \
            _Pragma("unroll")                                                \
            for (int i = 0; i < 16; ++i)                                     \
                rn[i] = p[(size_t)(skb * 16 + i) * D_DIM];                   \
            const float* an = abase + (size_t)((T) + 1) * BK;                \
            _Pragma("unroll")                                                \
            for (int kk = 0; kk < 4; ++kk) {                                 \
                RA_NXT[2 * kk] = __builtin_nontemporal_load(                 \
                    (const f32x4*)(an + kk * 32));                           \
                RA_NXT[2 * kk + 1] = __builtin_nontemporal_load(             \
                    (const f32x4*)(an + kk * 32 + 4));                       \
            }                                                                \
        }                                                                    \
        _Pragma("unroll")                                                    \
        for (int kk = 0; kk < 4; ++kk) {                                     \
            short8 a;                                                        \
            a[0] = f2bf(RA_CUR[2 * kk][0]);                                  \
            a[1] = f2bf(RA_CUR[2 * kk][1]);                                  \
            a[2] = f2bf(RA_CUR[2 * kk][2]);                                  \
            a[3] = f2bf(RA_CUR[2 * kk][3]);                                  \
            a[4] = f2bf(RA_CUR[2 * kk + 1][0]);                              \
            a[5] = f2bf(RA_CUR[2 * kk + 1][1]);                              \
            a[6] = f2bf(RA_CUR[2 * kk + 1][2]);                              \
            a[7] = f2bf(RA_CUR[2 * kk + 1][3]);                              \
            _Pragma("unroll")                                                \
            for (int ni = 0; ni < 4; ++ni) {                                 \
                const short8* bp = (const short8*)                           \
                    &lds_b[RBUF][ni * 16 + (lane & 15)][kk * 32 + kgrp];     \
                acc[ni] = __builtin_amdgcn_mfma_f32_16x16x32_bf16(           \
                    a, *bp, acc[ni], 0, 0, 0);                               \
            }                                                                \
        }                                                                    \
        if ((T) + 1 < NT) {                                                  \
            _Pragma("unroll")                                                \
            for (int j = 0; j < 4; ++j) {                                    \
                short4v v;                                                   \
                v[0] = f2bf(rn[4 * j + 0]);                                  \
                v[1] = f2bf(rn[4 * j + 1]);                                  \
                v[2] = f2bf(rn[4 * j + 2]);                                  \
                v[3] = f2bf(rn[4 * j + 3]);                                  \
                *(short4v*)&lds_b[(RBUF) ^ 1][sd][skb * 16 + 4 * j] = v;     \
            }                                                                \
        }                                                                    \
    }

    for (int t = 0; t < NT; t += 2) {
        ITER(t,     0, rA0, rA1);
        ITER(t + 1, 1, rA1, rA0);
    }
#undef ITER

    // ---- epilogue: C/D layout col = lane&15, row = (lane>>4)*4 + reg
    //      nontemporal stores: out is write-once, keep it out of L2.
    int col0 = lane & 15;
    int r0   = m0 + w * 16 + ((lane >> 4) << 2);
    float* ob = out + ((size_t)bh * S_DIM + r0) * D_DIM + col0;
#pragma unroll
    for (int ni = 0; ni < 4; ++ni) {
#pragma unroll
        for (int r = 0; r < 4; ++r)
            __builtin_nontemporal_store(acc[ni][r],
                                        ob + (size_t)r * D_DIM + ni * 16);
    }
}

extern "C" void kernel_launch(void* const* d_in, const int* in_sizes, int n_in,
                              void* d_out, int out_size, void* d_ws, size_t ws_size,
                              hipStream_t stream) {
    const float* x1 = (const float*)d_in[0];   // [2,16,2048,2048] softmax probs
    const float* x2 = (const float*)d_in[1];   // [2,16,2048,64]
    float* out = (float*)d_out;                // [2,16,2048,64]

    dim3 grid(512);   // 32 bh * 16 M-tiles
    dim3 block(512);  // 8 waves
    hipLaunchKernelGGL(pv_gemm_kernel, grid, block, 0, stream, x1, x2, out);
}